// Round 5
// baseline (350.370 us; speedup 1.0000x reference)
//
#include <hip/hip_runtime.h>
#include <hip/hip_bf16.h>
#include <stdint.h>

// Problem constants
#define M_REAL 36928LL      // 64*577
#define M_PAD  37120LL      // 145*256
#define DDIM   1024
#define SSEQ   577
#define NBATCH 64
#define NT     16           // K tiles (1024/64)

typedef __attribute__((ext_vector_type(8))) short bf16x8;
typedef __attribute__((ext_vector_type(4))) float f32x4;

// ws layout (bytes)
#define XBF_OFF   0ULL                  // 37120*1024*2 = 76,021,760
#define WBF_OFF   76021760ULL           // 1024*1024*2  =  2,097,152
#define ABF_OFF   78118912ULL           // 8*16*1024*2  =    262,144
#define XABF_OFF  78381056ULL           // 37120*32*2   =  2,375,680
#define GBBF_OFF  80756736ULL           // 64*1024*32*2 =  4,194,304
#define WS_NEED   84951040ULL

__device__ __forceinline__ unsigned short f2bf(float f) {
  union { float f; unsigned int u; } v; v.f = f;
  unsigned int u = v.u;
  unsigned int r = (u + 0x7fffu + ((u >> 16) & 1u)) >> 16;  // RNE
  return (unsigned short)r;
}

__device__ __forceinline__ bf16x8 cvt8(const float* __restrict__ p) {
  float4 a = *(const float4*)p;
  float4 b = *(const float4*)(p + 4);
  bf16x8 o;
  o[0] = (short)f2bf(a.x); o[1] = (short)f2bf(a.y);
  o[2] = (short)f2bf(a.z); o[3] = (short)f2bf(a.w);
  o[4] = (short)f2bf(b.x); o[5] = (short)f2bf(b.y);
  o[6] = (short)f2bf(b.z); o[7] = (short)f2bf(b.w);
  return o;
}

#define GLOAD_LDS16(gsrc, ldst)                                                  \
  __builtin_amdgcn_global_load_lds((const __attribute__((address_space(1))) void*)(gsrc), \
                                   (__attribute__((address_space(3))) void*)(ldst), 16, 0, 0)

// ---------------- kernel 1: cast x -> bf16, zero-pad rows to M_PAD ----------
__global__ void cast_x_kernel(const float* __restrict__ x,
                              unsigned short* __restrict__ xbf) {
  const long long NREAL = M_REAL * DDIM;
  const long long NTOT  = M_PAD * DDIM;
  long long t = (long long)blockIdx.x * blockDim.x + threadIdx.x;
  long long stride = (long long)gridDim.x * blockDim.x;
  for (long long i = t * 8; i < NTOT; i += stride * 8) {
    bf16x8 o;
    if (i < NREAL) {
      o = cvt8(x + i);
    } else {
#pragma unroll
      for (int j = 0; j < 8; ++j) o[j] = 0;
    }
    *(bf16x8*)(xbf + i) = o;
  }
}

// ---------------- kernel 2: prep (cast W, cast A, build gB, zero xa pad) ----
__global__ void prep_kernel(const float* __restrict__ W,
                            const float* __restrict__ A_all,
                            const float* __restrict__ B_all,
                            const int* __restrict__ idx,
                            const float* __restrict__ gates,
                            unsigned short* __restrict__ wbf,
                            unsigned short* __restrict__ abf,
                            unsigned short* __restrict__ gbbf,
                            unsigned short* __restrict__ xabf) {
  const int W_UNITS = 131072;                 // 8 elems each (1M total)
  const int A_UNITS = 16384;                  // 8 elems each (131072 total)
  const int G_UNITS = 65536;                  // one (b,n) row of 32 each
  const int P_UNITS = 6144;                   // xa pad elems (192 rows * 32)
  const int TOTAL = W_UNITS + A_UNITS + G_UNITS + P_UNITS;
  int u = blockIdx.x * blockDim.x + threadIdx.x;
  int stride = gridDim.x * blockDim.x;
  for (; u < TOTAL; u += stride) {
    if (u < W_UNITS) {
      int i = u * 8;
      *(bf16x8*)(wbf + i) = cvt8(W + i);
    } else if (u < W_UNITS + A_UNITS) {
      int i = (u - W_UNITS) * 8;
      *(bf16x8*)(abf + i) = cvt8(A_all + i);
    } else if (u < W_UNITS + A_UNITS + G_UNITS) {
      int v = u - W_UNITS - A_UNITS;
      int b = v >> 10;
      int n = v & 1023;
      unsigned short tmp[32];
#pragma unroll
      for (int k = 0; k < 2; ++k) {
        int e = idx[b * 2 + k];
        float g = gates[b * 2 + k];
        const float* Br = B_all + ((size_t)e * 1024 + n) * 16;
#pragma unroll
        for (int r = 0; r < 16; ++r) tmp[k * 16 + r] = f2bf(g * Br[r]);
      }
      unsigned short* dst = gbbf + (size_t)v * 32;
#pragma unroll
      for (int j = 0; j < 32; ++j) dst[j] = tmp[j];
    } else {
      int v = u - W_UNITS - A_UNITS - G_UNITS;
      xabf[(size_t)M_REAL * 32 + v] = 0;
    }
  }
}

// ---------------- kernel 3: xa = x @ A_sel^T  (per-b MFMA GEMM) -------------
__global__ __launch_bounds__(256) void xa_kernel(
    const unsigned short* __restrict__ xbf,
    const unsigned short* __restrict__ abf,
    const int* __restrict__ idx,
    unsigned short* __restrict__ xabf) {
  int bid = blockIdx.x;
  int b = bid / 10;
  int s0 = (bid % 10) * 64;
  int wave = threadIdx.x >> 6;
  int lane = threadIdx.x & 63;
  int l15 = lane & 15, lhi = lane >> 4;

  int srow = s0 + wave * 16 + l15;
  long long mrow = (long long)b * SSEQ + srow;     // < M_PAD
  const unsigned short* xrow = xbf + (size_t)mrow * DDIM;
  int e0 = idx[b * 2 + 0], e1 = idx[b * 2 + 1];
  const unsigned short* ar0 = abf + ((size_t)e0 * 16 + l15) * DDIM;
  const unsigned short* ar1 = abf + ((size_t)e1 * 16 + l15) * DDIM;

  f32x4 acc0 = {0.f, 0.f, 0.f, 0.f}, acc1 = {0.f, 0.f, 0.f, 0.f};
  for (int k = 0; k < DDIM; k += 32) {
    int ko = k + lhi * 8;
    bf16x8 a  = *(const bf16x8*)(xrow + ko);
    bf16x8 b0 = *(const bf16x8*)(ar0 + ko);
    bf16x8 b1 = *(const bf16x8*)(ar1 + ko);
    acc0 = __builtin_amdgcn_mfma_f32_16x16x32_bf16(a, b0, acc0, 0, 0, 0);
    acc1 = __builtin_amdgcn_mfma_f32_16x16x32_bf16(a, b1, acc1, 0, 0, 0);
  }
  int sout = s0 + wave * 16 + lhi * 4;
#pragma unroll
  for (int reg = 0; reg < 4; ++reg) {
    int s = sout + reg;
    if (s < SSEQ) {
      size_t mo = ((size_t)b * SSEQ + s) * 32;
      xabf[mo + l15]      = f2bf(acc0[reg]);
      xabf[mo + 16 + l15] = f2bf(acc1[reg]);
    }
  }
}

// ---------------- kernel 4: 256x256 BK=64 two-phase GEMM + LoRA + bias ------
// C[m,n] = sum_d x[m,d]*W[n,d] + bias[n] + sum_kr xa[m,kr]*gB[b(m),n,kr]
// Guide T3-minimum 2-phase recipe: STAGE(next) first, compute current,
// ONE vmcnt(0)+barrier per tile. Swizzle identical to round 3 (0 conflicts).
__global__ __launch_bounds__(512, 2) void gemm_kernel(
    const unsigned short* __restrict__ xbf,
    const unsigned short* __restrict__ wbf,
    const unsigned short* __restrict__ xabf,
    const unsigned short* __restrict__ gbbf,
    const float* __restrict__ bias,
    float* __restrict__ out) {
  __shared__ unsigned short As0[16384], As1[16384];   // 256x64 bf16 each
  __shared__ unsigned short Bs0[16384], Bs1[16384];

  // m204 bijective XCD-chunked swizzle: NWG=580 = 8*72 + 4
  int g = blockIdx.x;
  int xcd = g & 7, gi = g >> 3;
  int wg = (xcd < 4 ? xcd * 73 : 292 + (xcd - 4) * 72) + gi;
  const int bm = wg >> 2;                    // 0..144
  const int bn = wg & 3;                     // 0..3
  const long long m0 = (long long)bm * 256;
  const int n0 = bn * 256;
  const int tid = threadIdx.x;
  const int lane = tid & 63;
  const int wave = tid >> 6;
  const int l15 = lane & 15, lhi = lane >> 4;
  const int wmi = wave >> 2;                 // 0..1  (128-row half)
  const int wni = wave & 3;                  // 0..3  (64-col quarter)

  // ---- staging (global source pre-swizzled; LDS dest linear) ----
  const int rstage = tid >> 3;                                      // 0..63
  const int csrc = (((tid & 7) ^ (rstage & 7)) << 3);               // elems
  const unsigned short* gAp = xbf + (size_t)(m0 + rstage) * DDIM + csrc;
  const unsigned short* gBp = wbf + (size_t)(n0 + rstage) * DDIM + csrc;
  const int ldsbase = wave * 512;            // elems; wave-uniform, HW adds lane*16B

  // ---- fragment-read constants (swizzled ds_read addresses) ----
  const int sl0 = ((lhi ^ (l15 & 7)) << 3);  // elems, ks=0
  const int sl1 = sl0 ^ 32;                  // elems, ks=1 (XOR the ks bit)
  const int rowA0 = (wmi * 128 + l15) * 64;
  const int rowB0 = (wni * 64 + l15) * 64;

  f32x4 acc[8][4];
#pragma unroll
  for (int i = 0; i < 8; ++i)
#pragma unroll
    for (int j = 0; j < 4; ++j) acc[i][j] = (f32x4){0.f, 0.f, 0.f, 0.f};

#define STAGE(koff, As_, Bs_)                                                  \
  { _Pragma("unroll")                                                          \
    for (int l = 0; l < 4; ++l) {                                              \
      GLOAD_LDS16(gAp + (size_t)l * 64 * DDIM + (koff), &As_[l * 4096 + ldsbase]); \
      GLOAD_LDS16(gBp + (size_t)l * 64 * DDIM + (koff), &Bs_[l * 4096 + ldsbase]); \
    } }

#define BODY(As_, Bs_)                                                         \
  { bf16x8 bfr[4][2];                                                          \
    _Pragma("unroll")                                                          \
    for (int nf = 0; nf < 4; ++nf) {                                           \
      bfr[nf][0] = *(const bf16x8*)&Bs_[rowB0 + nf * 1024 + sl0];              \
      bfr[nf][1] = *(const bf16x8*)&Bs_[rowB0 + nf * 1024 + sl1];              \
    }                                                                          \
    _Pragma("unroll")                                                          \
    for (int mh = 0; mh < 2; ++mh) {                                           \
      bf16x8 afr[4][2];                                                        \
      _Pragma("unroll")                                                        \
      for (int f = 0; f < 4; ++f) {                                            \
        afr[f][0] = *(const bf16x8*)&As_[rowA0 + (mh * 64 + f * 16) * 64 + sl0]; \
        afr[f][1] = *(const bf16x8*)&As_[rowA0 + (mh * 64 + f * 16) * 64 + sl1]; \
      }                                                                        \
      __builtin_amdgcn_s_setprio(1);                                           \
      _Pragma("unroll")                                                        \
      for (int f = 0; f < 4; ++f)                                              \
        _Pragma("unroll")                                                      \
        for (int nf = 0; nf < 4; ++nf)                                         \
          _Pragma("unroll")                                                    \
          for (int ks = 0; ks < 2; ++ks)                                       \
            acc[mh * 4 + f][nf] = __builtin_amdgcn_mfma_f32_16x16x32_bf16(     \
                afr[f][ks], bfr[nf][ks], acc[mh * 4 + f][nf], 0, 0, 0);        \
      __builtin_amdgcn_s_setprio(0);                                           \
    } }

  // ---- prologue: stage tile 0, drain, barrier ----
  STAGE(0, As0, Bs0);
  asm volatile("s_waitcnt vmcnt(0)" ::: "memory");
  __builtin_amdgcn_s_barrier();
  asm volatile("" ::: "memory");

  // ---- main loop: 2 tiles per iteration, static buffers ----
  for (int t = 0; t < NT; t += 2) {          // t = 0,2,...,14
    STAGE((size_t)(t + 1) * 64, As1, Bs1);   // issue next-tile loads FIRST
    BODY(As0, Bs0);
    asm volatile("s_waitcnt vmcnt(0) lgkmcnt(0)" ::: "memory");
    __builtin_amdgcn_s_barrier();
    asm volatile("" ::: "memory");
    if (t + 2 < NT) {
      STAGE((size_t)(t + 2) * 64, As0, Bs0);
      BODY(As1, Bs1);
      asm volatile("s_waitcnt vmcnt(0) lgkmcnt(0)" ::: "memory");
      __builtin_amdgcn_s_barrier();
      asm volatile("" ::: "memory");
    } else {
      BODY(As1, Bs1);                        // final tile, no trailing sync
    }
  }
#undef STAGE
#undef BODY

  // ---- LoRA rank-32 extra K-steps, masked per batch (tile spans <= 2) ----
  long long mlast = m0 + 255; if (mlast > M_REAL - 1) mlast = M_REAL - 1;
  int b_lo = (int)(m0 / SSEQ);
  int b_hi = (int)(mlast / SSEQ);
  for (int bs = b_lo; bs <= b_hi; ++bs) {
    bf16x8 gb[4];
#pragma unroll
    for (int nf = 0; nf < 4; ++nf) {
      int n = n0 + wni * 64 + nf * 16 + l15;
      gb[nf] = *(const bf16x8*)&gbbf[((size_t)bs * 1024 + n) * 32 + lhi * 8];
    }
#pragma unroll
    for (int f8 = 0; f8 < 8; ++f8) {
      long long m = m0 + wmi * 128 + f8 * 16 + l15;
      bf16x8 av = *(const bf16x8*)&xabf[(size_t)m * 32 + lhi * 8];  // pad rows zero
      if ((int)(m / SSEQ) != bs) {
#pragma unroll
        for (int j = 0; j < 8; ++j) av[j] = 0;
      }
#pragma unroll
      for (int nf = 0; nf < 4; ++nf)
        acc[f8][nf] = __builtin_amdgcn_mfma_f32_16x16x32_bf16(av, gb[nf], acc[f8][nf], 0, 0, 0);
    }
  }

  // ---- epilogue: + bias, store fp32 ----
  float bv[4];
#pragma unroll
  for (int nf = 0; nf < 4; ++nf) bv[nf] = bias[n0 + wni * 64 + nf * 16 + l15];
#pragma unroll
  for (int f8 = 0; f8 < 8; ++f8) {
#pragma unroll
    for (int nf = 0; nf < 4; ++nf) {
      int n = n0 + wni * 64 + nf * 16 + l15;
#pragma unroll
      for (int r = 0; r < 4; ++r) {
        long long m = m0 + wmi * 128 + f8 * 16 + lhi * 4 + r;
        if (m < M_REAL) out[m * DDIM + n] = acc[f8][nf][r] + bv[nf];
      }
    }
  }
}

extern "C" void kernel_launch(void* const* d_in, const int* in_sizes, int n_in,
                              void* d_out, int out_size, void* d_ws, size_t ws_size,
                              hipStream_t stream) {
  const float* x      = (const float*)d_in[0];
  const int*   idx    = (const int*)d_in[1];
  const float* gates  = (const float*)d_in[2];
  const float* W      = (const float*)d_in[3];
  const float* A_all  = (const float*)d_in[4];
  const float* B_all  = (const float*)d_in[5];
  const float* bias   = (const float*)d_in[6];
  float* out = (float*)d_out;

  char* ws = (char*)d_ws;
  unsigned short* xbf  = (unsigned short*)(ws + XBF_OFF);
  unsigned short* wbf  = (unsigned short*)(ws + WBF_OFF);
  unsigned short* abf  = (unsigned short*)(ws + ABF_OFF);
  unsigned short* xabf = (unsigned short*)(ws + XABF_OFF);
  unsigned short* gbbf = (unsigned short*)(ws + GBBF_OFF);

  cast_x_kernel<<<dim3(2048), dim3(256), 0, stream>>>(x, xbf);
  prep_kernel<<<dim3(840), dim3(256), 0, stream>>>(W, A_all, B_all, idx, gates,
                                                   wbf, abf, gbbf, xabf);
  xa_kernel<<<dim3(640), dim3(256), 0, stream>>>(xbf, abf, idx, xabf);
  gemm_kernel<<<dim3(580), dim3(512), 0, stream>>>(xbf, wbf, xabf, gbbf, bias, out);
}

// Round 6
// 225.346 us; speedup vs baseline: 1.5548x; 1.5548x over previous
//
#include <hip/hip_runtime.h>
#include <hip/hip_bf16.h>
#include <stdint.h>

// Problem constants
#define M_REAL 36928LL      // 64*577
#define M_PAD  36992LL      // 289*128
#define DDIM   1024
#define SSEQ   577
#define NBATCH 64

typedef __attribute__((ext_vector_type(8))) short bf16x8;
typedef __attribute__((ext_vector_type(4))) float f32x4;

// ws layout (bytes)
#define XBF_OFF   0ULL                  // 36992*1024*2 = 75,759,616
#define WBF_OFF   75759616ULL           // 1024*1024*2  =  2,097,152
#define ABF_OFF   77856768ULL           // 8*16*1024*2  =    262,144
#define XABF_OFF  78118912ULL           // 36992*32*2   =  2,367,488
#define GBBF_OFF  80486400ULL           // 64*1024*32*2 =  4,194,304
#define WS_NEED   84680704ULL

__device__ __forceinline__ unsigned short f2bf(float f) {
  union { float f; unsigned int u; } v; v.f = f;
  unsigned int u = v.u;
  unsigned int r = (u + 0x7fffu + ((u >> 16) & 1u)) >> 16;  // RNE
  return (unsigned short)r;
}

__device__ __forceinline__ bf16x8 cvt8(const float* __restrict__ p) {
  float4 a = *(const float4*)p;
  float4 b = *(const float4*)(p + 4);
  bf16x8 o;
  o[0] = (short)f2bf(a.x); o[1] = (short)f2bf(a.y);
  o[2] = (short)f2bf(a.z); o[3] = (short)f2bf(a.w);
  o[4] = (short)f2bf(b.x); o[5] = (short)f2bf(b.y);
  o[6] = (short)f2bf(b.z); o[7] = (short)f2bf(b.w);
  return o;
}

#define GLOAD_LDS16(gsrc, ldst)                                                  \
  __builtin_amdgcn_global_load_lds((const __attribute__((address_space(1))) void*)(gsrc), \
                                   (__attribute__((address_space(3))) void*)(ldst), 16, 0, 0)

// ---------------- kernel 1: cast x -> bf16, zero-pad rows to M_PAD ----------
__global__ void cast_x_kernel(const float* __restrict__ x,
                              unsigned short* __restrict__ xbf) {
  const long long NREAL = M_REAL * DDIM;
  const long long NTOT  = M_PAD * DDIM;
  long long t = (long long)blockIdx.x * blockDim.x + threadIdx.x;
  long long stride = (long long)gridDim.x * blockDim.x;
  for (long long i = t * 8; i < NTOT; i += stride * 8) {
    bf16x8 o;
    if (i < NREAL) {
      o = cvt8(x + i);
    } else {
#pragma unroll
      for (int j = 0; j < 8; ++j) o[j] = 0;
    }
    *(bf16x8*)(xbf + i) = o;
  }
}

// ---------------- kernel 2: prep (cast W, cast A, build gB, zero xa pad) ----
__global__ void prep_kernel(const float* __restrict__ W,
                            const float* __restrict__ A_all,
                            const float* __restrict__ B_all,
                            const int* __restrict__ idx,
                            const float* __restrict__ gates,
                            unsigned short* __restrict__ wbf,
                            unsigned short* __restrict__ abf,
                            unsigned short* __restrict__ gbbf,
                            unsigned short* __restrict__ xabf) {
  const int W_UNITS = 131072;                 // 8 elems each (1M total)
  const int A_UNITS = 16384;                  // 8 elems each (131072 total)
  const int G_UNITS = 65536;                  // one (b,n) row of 32 each
  const int P_UNITS = 2048;                   // xa pad elems (64 rows * 32)
  const int TOTAL = W_UNITS + A_UNITS + G_UNITS + P_UNITS;
  int u = blockIdx.x * blockDim.x + threadIdx.x;
  int stride = gridDim.x * blockDim.x;
  for (; u < TOTAL; u += stride) {
    if (u < W_UNITS) {
      int i = u * 8;
      *(bf16x8*)(wbf + i) = cvt8(W + i);
    } else if (u < W_UNITS + A_UNITS) {
      int i = (u - W_UNITS) * 8;
      *(bf16x8*)(abf + i) = cvt8(A_all + i);
    } else if (u < W_UNITS + A_UNITS + G_UNITS) {
      int v = u - W_UNITS - A_UNITS;
      int b = v >> 10;
      int n = v & 1023;
      unsigned short tmp[32];
#pragma unroll
      for (int k = 0; k < 2; ++k) {
        int e = idx[b * 2 + k];
        float g = gates[b * 2 + k];
        const float* Br = B_all + ((size_t)e * 1024 + n) * 16;
#pragma unroll
        for (int r = 0; r < 16; ++r) tmp[k * 16 + r] = f2bf(g * Br[r]);
      }
      unsigned short* dst = gbbf + (size_t)v * 32;
#pragma unroll
      for (int j = 0; j < 32; ++j) dst[j] = tmp[j];
    } else {
      int v = u - W_UNITS - A_UNITS - G_UNITS;
      xabf[(size_t)M_REAL * 32 + v] = 0;
    }
  }
}

// ---------------- kernel 3: xa = x @ A_sel^T  (per-b MFMA GEMM) -------------
__global__ __launch_bounds__(256) void xa_kernel(
    const unsigned short* __restrict__ xbf,
    const unsigned short* __restrict__ abf,
    const int* __restrict__ idx,
    unsigned short* __restrict__ xabf) {
  int bid = blockIdx.x;
  int b = bid / 10;
  int s0 = (bid % 10) * 64;
  int wave = threadIdx.x >> 6;
  int lane = threadIdx.x & 63;
  int l15 = lane & 15, lhi = lane >> 4;

  int srow = s0 + wave * 16 + l15;
  long long mrow = (long long)b * SSEQ + srow;     // < M_PAD
  const unsigned short* xrow = xbf + (size_t)mrow * DDIM;
  int e0 = idx[b * 2 + 0], e1 = idx[b * 2 + 1];
  const unsigned short* ar0 = abf + ((size_t)e0 * 16 + l15) * DDIM;
  const unsigned short* ar1 = abf + ((size_t)e1 * 16 + l15) * DDIM;

  f32x4 acc0 = {0.f, 0.f, 0.f, 0.f}, acc1 = {0.f, 0.f, 0.f, 0.f};
  for (int k = 0; k < DDIM; k += 32) {
    int ko = k + lhi * 8;
    bf16x8 a  = *(const bf16x8*)(xrow + ko);
    bf16x8 b0 = *(const bf16x8*)(ar0 + ko);
    bf16x8 b1 = *(const bf16x8*)(ar1 + ko);
    acc0 = __builtin_amdgcn_mfma_f32_16x16x32_bf16(a, b0, acc0, 0, 0, 0);
    acc1 = __builtin_amdgcn_mfma_f32_16x16x32_bf16(a, b1, acc1, 0, 0, 0);
  }
  int sout = s0 + wave * 16 + lhi * 4;
#pragma unroll
  for (int reg = 0; reg < 4; ++reg) {
    int s = sout + reg;
    if (s < SSEQ) {
      size_t mo = ((size_t)b * SSEQ + s) * 32;
      xabf[mo + l15]      = f2bf(acc0[reg]);
      xabf[mo + 16 + l15] = f2bf(acc1[reg]);
    }
  }
}

// ---------------- kernel 4: 128x128 m97-structure GEMM + swizzles -----------
// C[m,n] = sum_d x[m,d]*W[n,d] + bias[n] + sum_kr xa[m,kr]*gB[b(m),n,kr]
// Round-1 structure (best measured) + BK=64 XOR LDS swizzle (0-conflict,
// verified r3/r5) + bijective XCD block swizzle (2312 = 8*289 exact).
#define BM 128
#define BN 128
#define BKT 64
__global__ __launch_bounds__(256, 4) void gemm_kernel(
    const unsigned short* __restrict__ xbf,
    const unsigned short* __restrict__ wbf,
    const unsigned short* __restrict__ xabf,
    const unsigned short* __restrict__ gbbf,
    const float* __restrict__ bias,
    float* __restrict__ out) {
  __shared__ unsigned short As[BM * BKT];   // 16 KiB
  __shared__ unsigned short Bs[BN * BKT];   // 16 KiB

  // XCD-chunked bijective swizzle: 2312 blocks = 8 XCDs x 289
  int g = blockIdx.x;
  int xcd = g & 7, gi = g >> 3;
  int wg = xcd * 289 + gi;
  const int bm = wg >> 3;              // 0..288
  const int bn = wg & 7;               // 0..7
  const long long m0 = (long long)bm * BM;
  const int n0 = bn * BN;

  const int tid = threadIdx.x;
  const int wave = tid >> 6, lane = tid & 63;
  const int l15 = lane & 15, lhi = lane >> 4;
  const int wm = (wave >> 1) * 64, wn = (wave & 1) * 64;

  f32x4 acc[4][4];
#pragma unroll
  for (int i = 0; i < 4; ++i)
#pragma unroll
    for (int j = 0; j < 4; ++j) acc[i][j] = (f32x4){0.f, 0.f, 0.f, 0.f};

  // staging: wave stages 32 rows; row = wave*32 + i*8 + (lane>>3), chunk=lane&7
  // swizzle: LDS[row][q] = global[row][q ^ (row&7)]; row&7 = lane>>3
  const int rowbase = wave * 32;
  const int rl = lane >> 3;
  const int csrc = (((lane & 7) ^ rl) << 3);   // elems

  // frag reads: desired chunk q = ks*4+lhi -> LDS chunk q ^ (l15&7)
  const int sl0 = ((lhi ^ (l15 & 7)) << 3);
  const int sl1 = sl0 ^ 32;

  for (int k0 = 0; k0 < DDIM; k0 += BKT) {
#pragma unroll
    for (int i = 0; i < 4; ++i) {
      int r = rowbase + i * 8;
      GLOAD_LDS16(xbf + (size_t)(m0 + r + rl) * DDIM + k0 + csrc, &As[r * BKT]);
      GLOAD_LDS16(wbf + (size_t)(n0 + r + rl) * DDIM + k0 + csrc, &Bs[r * BKT]);
    }
    __syncthreads();
    {
      bf16x8 af[4][2], bfv[4][2];
#pragma unroll
      for (int f = 0; f < 4; ++f) {
        af[f][0]  = *(const bf16x8*)&As[(wm + f * 16 + l15) * BKT + sl0];
        af[f][1]  = *(const bf16x8*)&As[(wm + f * 16 + l15) * BKT + sl1];
        bfv[f][0] = *(const bf16x8*)&Bs[(wn + f * 16 + l15) * BKT + sl0];
        bfv[f][1] = *(const bf16x8*)&Bs[(wn + f * 16 + l15) * BKT + sl1];
      }
#pragma unroll
      for (int i = 0; i < 4; ++i)
#pragma unroll
        for (int j = 0; j < 4; ++j)
#pragma unroll
          for (int ks = 0; ks < 2; ++ks)
            acc[i][j] = __builtin_amdgcn_mfma_f32_16x16x32_bf16(
                af[i][ks], bfv[j][ks], acc[i][j], 0, 0, 0);
    }
    __syncthreads();
  }

  // LoRA rank-32 extra K-steps, masked per batch (128-row tile spans <= 2)
  long long mlast = m0 + BM - 1; if (mlast > M_REAL - 1) mlast = M_REAL - 1;
  int b_lo = (int)(m0 / SSEQ);
  int b_hi = (int)(mlast / SSEQ);
  for (int bs = b_lo; bs <= b_hi; ++bs) {
    bf16x8 af[4], bfv[4];
#pragma unroll
    for (int f = 0; f < 4; ++f) {
      long long m = m0 + wm + f * 16 + l15;
      bf16x8 v = *(const bf16x8*)&xabf[(size_t)m * 32 + lhi * 8];  // pad rows zero
      if ((int)(m / SSEQ) != bs) {
#pragma unroll
        for (int j = 0; j < 8; ++j) v[j] = 0;
      }
      af[f] = v;
      int n = n0 + wn + f * 16 + l15;
      bfv[f] = *(const bf16x8*)&gbbf[((size_t)bs * 1024 + n) * 32 + lhi * 8];
    }
#pragma unroll
    for (int i = 0; i < 4; ++i)
#pragma unroll
      for (int j = 0; j < 4; ++j)
        acc[i][j] = __builtin_amdgcn_mfma_f32_16x16x32_bf16(af[i], bfv[j], acc[i][j], 0, 0, 0);
  }

  // epilogue: + bias, store fp32
#pragma unroll
  for (int i = 0; i < 4; ++i) {
#pragma unroll
    for (int j = 0; j < 4; ++j) {
      int n = n0 + wn + j * 16 + l15;
      float bv = bias[n];
#pragma unroll
      for (int reg = 0; reg < 4; ++reg) {
        long long m = m0 + wm + i * 16 + lhi * 4 + reg;
        if (m < M_REAL) out[m * DDIM + n] = acc[i][j][reg] + bv;
      }
    }
  }
}

extern "C" void kernel_launch(void* const* d_in, const int* in_sizes, int n_in,
                              void* d_out, int out_size, void* d_ws, size_t ws_size,
                              hipStream_t stream) {
  const float* x      = (const float*)d_in[0];
  const int*   idx    = (const int*)d_in[1];
  const float* gates  = (const float*)d_in[2];
  const float* W      = (const float*)d_in[3];
  const float* A_all  = (const float*)d_in[4];
  const float* B_all  = (const float*)d_in[5];
  const float* bias   = (const float*)d_in[6];
  float* out = (float*)d_out;

  char* ws = (char*)d_ws;
  unsigned short* xbf  = (unsigned short*)(ws + XBF_OFF);
  unsigned short* wbf  = (unsigned short*)(ws + WBF_OFF);
  unsigned short* abf  = (unsigned short*)(ws + ABF_OFF);
  unsigned short* xabf = (unsigned short*)(ws + XABF_OFF);
  unsigned short* gbbf = (unsigned short*)(ws + GBBF_OFF);

  cast_x_kernel<<<dim3(2048), dim3(256), 0, stream>>>(x, xbf);
  prep_kernel<<<dim3(840), dim3(256), 0, stream>>>(W, A_all, B_all, idx, gates,
                                                   wbf, abf, gbbf, xabf);
  xa_kernel<<<dim3(640), dim3(256), 0, stream>>>(xbf, abf, idx, xabf);
  gemm_kernel<<<dim3(2312), dim3(256), 0, stream>>>(xbf, wbf, xabf, gbbf, bias, out);
}

// Round 7
// 224.680 us; speedup vs baseline: 1.5594x; 1.0030x over previous
//
#include <hip/hip_runtime.h>
#include <hip/hip_bf16.h>
#include <stdint.h>

// Problem constants
#define M_REAL 36928LL      // 64*577
#define M_PAD  37120LL      // 145*256
#define DDIM   1024
#define SSEQ   577
#define NBATCH 64
#define NT     16           // K tiles (1024/64)

typedef __attribute__((ext_vector_type(8))) short bf16x8;
typedef __attribute__((ext_vector_type(4))) float f32x4;

// ws layout (bytes)
#define XBF_OFF   0ULL                  // 37120*1024*2 = 76,021,760
#define WBF_OFF   76021760ULL           // 1024*1024*2  =  2,097,152
#define ABF_OFF   78118912ULL           // 8*16*1024*2  =    262,144
#define XABF_OFF  78381056ULL           // 37120*32*2   =  2,375,680
#define GBBF_OFF  80756736ULL           // 64*1024*32*2 =  4,194,304
#define WS_NEED   84951040ULL

__device__ __forceinline__ unsigned short f2bf(float f) {
  union { float f; unsigned int u; } v; v.f = f;
  unsigned int u = v.u;
  unsigned int r = (u + 0x7fffu + ((u >> 16) & 1u)) >> 16;  // RNE
  return (unsigned short)r;
}

__device__ __forceinline__ bf16x8 cvt8(const float* __restrict__ p) {
  float4 a = *(const float4*)p;
  float4 b = *(const float4*)(p + 4);
  bf16x8 o;
  o[0] = (short)f2bf(a.x); o[1] = (short)f2bf(a.y);
  o[2] = (short)f2bf(a.z); o[3] = (short)f2bf(a.w);
  o[4] = (short)f2bf(b.x); o[5] = (short)f2bf(b.y);
  o[6] = (short)f2bf(b.z); o[7] = (short)f2bf(b.w);
  return o;
}

#define GLOAD_LDS16(gsrc, ldst)                                                  \
  __builtin_amdgcn_global_load_lds((const __attribute__((address_space(1))) void*)(gsrc), \
                                   (__attribute__((address_space(3))) void*)(ldst), 16, 0, 0)

// ---------------- kernel 1: cast x -> bf16, zero-pad rows to M_PAD ----------
__global__ void cast_x_kernel(const float* __restrict__ x,
                              unsigned short* __restrict__ xbf) {
  const long long NREAL = M_REAL * DDIM;
  const long long NTOT  = M_PAD * DDIM;
  long long t = (long long)blockIdx.x * blockDim.x + threadIdx.x;
  long long stride = (long long)gridDim.x * blockDim.x;
  for (long long i = t * 8; i < NTOT; i += stride * 8) {
    bf16x8 o;
    if (i < NREAL) {
      o = cvt8(x + i);
    } else {
#pragma unroll
      for (int j = 0; j < 8; ++j) o[j] = 0;
    }
    *(bf16x8*)(xbf + i) = o;
  }
}

// ---------------- kernel 2: prep (cast W, cast A, build gB, zero xa pad) ----
__global__ void prep_kernel(const float* __restrict__ W,
                            const float* __restrict__ A_all,
                            const float* __restrict__ B_all,
                            const int* __restrict__ idx,
                            const float* __restrict__ gates,
                            unsigned short* __restrict__ wbf,
                            unsigned short* __restrict__ abf,
                            unsigned short* __restrict__ gbbf,
                            unsigned short* __restrict__ xabf) {
  const int W_UNITS = 131072;                 // 8 elems each (1M total)
  const int A_UNITS = 16384;                  // 8 elems each (131072 total)
  const int G_UNITS = 65536;                  // one (b,n) row of 32 each
  const int P_UNITS = 6144;                   // xa pad elems (192 rows * 32)
  const int TOTAL = W_UNITS + A_UNITS + G_UNITS + P_UNITS;
  int u = blockIdx.x * blockDim.x + threadIdx.x;
  int stride = gridDim.x * blockDim.x;
  for (; u < TOTAL; u += stride) {
    if (u < W_UNITS) {
      int i = u * 8;
      *(bf16x8*)(wbf + i) = cvt8(W + i);
    } else if (u < W_UNITS + A_UNITS) {
      int i = (u - W_UNITS) * 8;
      *(bf16x8*)(abf + i) = cvt8(A_all + i);
    } else if (u < W_UNITS + A_UNITS + G_UNITS) {
      int v = u - W_UNITS - A_UNITS;
      int b = v >> 10;
      int n = v & 1023;
      unsigned short tmp[32];
#pragma unroll
      for (int k = 0; k < 2; ++k) {
        int e = idx[b * 2 + k];
        float g = gates[b * 2 + k];
        const float* Br = B_all + ((size_t)e * 1024 + n) * 16;
#pragma unroll
        for (int r = 0; r < 16; ++r) tmp[k * 16 + r] = f2bf(g * Br[r]);
      }
      unsigned short* dst = gbbf + (size_t)v * 32;
#pragma unroll
      for (int j = 0; j < 32; ++j) dst[j] = tmp[j];
    } else {
      int v = u - W_UNITS - A_UNITS - G_UNITS;
      xabf[(size_t)M_REAL * 32 + v] = 0;
    }
  }
}

// ---------------- kernel 3: xa = x @ A_sel^T  (per-b MFMA GEMM) -------------
__global__ __launch_bounds__(256) void xa_kernel(
    const unsigned short* __restrict__ xbf,
    const unsigned short* __restrict__ abf,
    const int* __restrict__ idx,
    unsigned short* __restrict__ xabf) {
  int bid = blockIdx.x;
  int b = bid / 10;
  int s0 = (bid % 10) * 64;
  int wave = threadIdx.x >> 6;
  int lane = threadIdx.x & 63;
  int l15 = lane & 15, lhi = lane >> 4;

  int srow = s0 + wave * 16 + l15;
  long long mrow = (long long)b * SSEQ + srow;     // < M_PAD
  const unsigned short* xrow = xbf + (size_t)mrow * DDIM;
  int e0 = idx[b * 2 + 0], e1 = idx[b * 2 + 1];
  const unsigned short* ar0 = abf + ((size_t)e0 * 16 + l15) * DDIM;
  const unsigned short* ar1 = abf + ((size_t)e1 * 16 + l15) * DDIM;

  f32x4 acc0 = {0.f, 0.f, 0.f, 0.f}, acc1 = {0.f, 0.f, 0.f, 0.f};
  for (int k = 0; k < DDIM; k += 32) {
    int ko = k + lhi * 8;
    bf16x8 a  = *(const bf16x8*)(xrow + ko);
    bf16x8 b0 = *(const bf16x8*)(ar0 + ko);
    bf16x8 b1 = *(const bf16x8*)(ar1 + ko);
    acc0 = __builtin_amdgcn_mfma_f32_16x16x32_bf16(a, b0, acc0, 0, 0, 0);
    acc1 = __builtin_amdgcn_mfma_f32_16x16x32_bf16(a, b1, acc1, 0, 0, 0);
  }
  int sout = s0 + wave * 16 + lhi * 4;
#pragma unroll
  for (int reg = 0; reg < 4; ++reg) {
    int s = sout + reg;
    if (s < SSEQ) {
      size_t mo = ((size_t)b * SSEQ + s) * 32;
      xabf[mo + l15]      = f2bf(acc0[reg]);
      xabf[mo + 16 + l15] = f2bf(acc1[reg]);
    }
  }
}

// ---------------- kernel 4: 256x256 8-phase (m201 template) GEMM ------------
// C[m,n] = sum_d x[m,d]*W[n,d] + bias[n] + sum_kr xa[m,kr]*gB[b(m),n,kr]
// 2 K-tiles/iter (parity dbufs), 8 phases/iter, 1 half-tile staged/phase,
// counted vmcnt(4) at phases 4 & 8 only. Swizzle = r3/r6 verified XOR.
__global__ __launch_bounds__(512, 2) void gemm_kernel(
    const unsigned short* __restrict__ xbf,
    const unsigned short* __restrict__ wbf,
    const unsigned short* __restrict__ xabf,
    const unsigned short* __restrict__ gbbf,
    const float* __restrict__ bias,
    float* __restrict__ out) {
  __shared__ unsigned short Ab[2][2][8192];   // [parity][half][128*64] = 64 KiB
  __shared__ unsigned short Bb[2][2][8192];   // 64 KiB

  // m204 bijective XCD-chunked swizzle: NWG=580 = 8*72 + 4
  int g = blockIdx.x;
  int xcd = g & 7, gi = g >> 3;
  int wg = (xcd < 4 ? xcd * 73 : 292 + (xcd - 4) * 72) + gi;
  const int bm = wg >> 2;                    // 0..144
  const int bn = wg & 3;                     // 0..3
  const long long m0 = (long long)bm * 256;
  const int n0 = bn * 256;
  const int tid = threadIdx.x;
  const int lane = tid & 63;
  const int wave = tid >> 6;
  const int l15 = lane & 15, lhi = lane >> 4;
  const int wmi = wave >> 2;                 // 0..1  -> A half
  const int wni = wave & 3;                  // 0..3

  // staging: per half-tile 2 gloads/thread; row = l*64 + (tid>>3), chunk=tid&7
  const int srow = tid >> 3;                                     // 0..63
  const int csrc = (((tid & 7) ^ (srow & 7)) << 3);              // pre-swizzled src
  const unsigned short* gAp = xbf + (size_t)(m0 + srow) * DDIM + csrc;
  const unsigned short* gBp = wbf + (size_t)(n0 + srow) * DDIM + csrc;
  const int ldsb = wave * 512;               // wave-uniform; HW adds lane*16B

  // fragment reads (swizzled): chunk = (ks*4+lhi) ^ (row&7), row&7 = l15&7
  const int sl0 = ((lhi ^ (l15 & 7)) << 3);
  const int sl1 = sl0 ^ 32;
  const int hB = wni >> 1, rB0 = (wni & 1) * 64;

  f32x4 acc[8][4];
#pragma unroll
  for (int i = 0; i < 8; ++i)
#pragma unroll
    for (int j = 0; j < 4; ++j) acc[i][j] = (f32x4){0.f, 0.f, 0.f, 0.f};

#define STAGE_A(par, t, h)                                                      \
  do {                                                                          \
    GLOAD_LDS16(gAp + (size_t)((h) * 128) * DDIM + (size_t)(t) * 64,            \
                &Ab[par][h][ldsb]);                                             \
    GLOAD_LDS16(gAp + (size_t)((h) * 128 + 64) * DDIM + (size_t)(t) * 64,       \
                &Ab[par][h][4096 + ldsb]);                                      \
  } while (0)
#define STAGE_B(par, t, h)                                                      \
  do {                                                                          \
    GLOAD_LDS16(gBp + (size_t)((h) * 128) * DDIM + (size_t)(t) * 64,            \
                &Bb[par][h][ldsb]);                                             \
    GLOAD_LDS16(gBp + (size_t)((h) * 128 + 64) * DDIM + (size_t)(t) * 64,       \
                &Bb[par][h][4096 + ldsb]);                                      \
  } while (0)
#define NOSTAGE do {} while (0)
#define VM4() asm volatile("s_waitcnt vmcnt(4)" ::: "memory")
#define VM0() asm volatile("s_waitcnt vmcnt(0)" ::: "memory")
#define VMNONE do {} while (0)
#define BAR() do { __builtin_amdgcn_s_barrier(); asm volatile("" ::: "memory"); } while (0)
#define LGKM0() asm volatile("s_waitcnt lgkmcnt(0)" ::: "memory")
#define LGKM8() asm volatile("s_waitcnt lgkmcnt(8)" ::: "memory")

#define DS_B(par, bfr)                                                          \
  do { _Pragma("unroll") for (int nf = 0; nf < 4; ++nf) {                       \
    bfr[nf][0] = *(const bf16x8*)&Bb[par][hB][(rB0 + nf * 16 + l15) * 64 + sl0];\
    bfr[nf][1] = *(const bf16x8*)&Bb[par][hB][(rB0 + nf * 16 + l15) * 64 + sl1];\
  } } while (0)
#define DS_A2(par, q, af)                                                       \
  do { _Pragma("unroll") for (int j = 0; j < 2; ++j) {                          \
    af[j][0] = *(const bf16x8*)&Ab[par][wmi][((2*(q)+j)*16 + l15)*64 + sl0];    \
    af[j][1] = *(const bf16x8*)&Ab[par][wmi][((2*(q)+j)*16 + l15)*64 + sl1];    \
  } } while (0)
#define MFMA_Q(q, af, bfr)                                                      \
  do { __builtin_amdgcn_s_setprio(1);                                           \
    _Pragma("unroll") for (int j = 0; j < 2; ++j)                               \
      _Pragma("unroll") for (int nf = 0; nf < 4; ++nf)                          \
        _Pragma("unroll") for (int ks = 0; ks < 2; ++ks)                        \
          acc[2*(q)+j][nf] = __builtin_amdgcn_mfma_f32_16x16x32_bf16(           \
              af[j][ks], bfr[nf][ks], acc[2*(q)+j][nf], 0, 0, 0);               \
    __builtin_amdgcn_s_setprio(0); } while (0)

#define PH1(par, bfr, af, STG) do { DS_B(par, bfr); DS_A2(par, 0, af); STG;     \
    LGKM8(); BAR(); LGKM0(); MFMA_Q(0, af, bfr); BAR(); } while (0)
#define PHm(par, q, bfr, af, STG) do { DS_A2(par, q, af); STG;                  \
    BAR(); LGKM0(); MFMA_Q(q, af, bfr); BAR(); } while (0)
#define PH4(par, bfr, af, STG, VMW) do { DS_A2(par, 3, af); STG;                \
    BAR(); LGKM0(); MFMA_Q(3, af, bfr); VMW; BAR(); } while (0)

  // ---- prologue: A(0),B(0) fully; B(1) in flight ----
  STAGE_A(0, 0, 0); STAGE_A(0, 0, 1);
  STAGE_B(0, 0, 0); STAGE_B(0, 0, 1);
  STAGE_B(1, 1, 0); STAGE_B(1, 1, 1);
  VM4();                                     // A(0),B(0) landed; B(1) flying
  BAR();

  // ---- main loop: iterations 0..6 (tiles 2i, 2i+1) ----
  for (int i = 0; i < 7; ++i) {
    const int t = 2 * i;
    bf16x8 bfrE[4][2], bfrO[4][2], af[2][2];
    PH1(0,    bfrE, af, STAGE_A(1, t + 1, 0));
    PHm(0, 1, bfrE, af, STAGE_A(1, t + 1, 1));
    PHm(0, 2, bfrE, af, STAGE_B(0, t + 2, 0));
    PH4(0,    bfrE, af, STAGE_B(0, t + 2, 1), VM4());  // A(t+1),B(t+1) landed
    PH1(1,    bfrO, af, STAGE_A(0, t + 2, 0));
    PHm(1, 1, bfrO, af, STAGE_A(0, t + 2, 1));
    PHm(1, 2, bfrO, af, STAGE_B(1, t + 3, 0));
    PH4(1,    bfrO, af, STAGE_B(1, t + 3, 1), VM4());  // A(t+2),B(t+2) landed
  }
  // ---- peeled final iteration (tiles 14,15) ----
  {
    bf16x8 bfrE[4][2], bfrO[4][2], af[2][2];
    PH1(0,    bfrE, af, STAGE_A(1, 15, 0));
    PHm(0, 1, bfrE, af, STAGE_A(1, 15, 1));
    PHm(0, 2, bfrE, af, NOSTAGE);
    PH4(0,    bfrE, af, NOSTAGE, VM0());               // drain: A(15),B(15) landed
    PH1(1,    bfrO, af, NOSTAGE);
    PHm(1, 1, bfrO, af, NOSTAGE);
    PHm(1, 2, bfrO, af, NOSTAGE);
    PH4(1,    bfrO, af, NOSTAGE, VMNONE);
  }
#undef STAGE_A
#undef STAGE_B
#undef PH1
#undef PHm
#undef PH4

  // ---- LoRA rank-32 extra K-steps, masked per batch (tile spans <= 2) ----
  long long mlast = m0 + 255; if (mlast > M_REAL - 1) mlast = M_REAL - 1;
  int b_lo = (int)(m0 / SSEQ);
  int b_hi = (int)(mlast / SSEQ);
  for (int bs = b_lo; bs <= b_hi; ++bs) {
    bf16x8 gb[4];
#pragma unroll
    for (int nf = 0; nf < 4; ++nf) {
      int n = n0 + wni * 64 + nf * 16 + l15;
      gb[nf] = *(const bf16x8*)&gbbf[((size_t)bs * 1024 + n) * 32 + lhi * 8];
    }
#pragma unroll
    for (int f8 = 0; f8 < 8; ++f8) {
      long long m = m0 + wmi * 128 + f8 * 16 + l15;
      bf16x8 av = *(const bf16x8*)&xabf[(size_t)m * 32 + lhi * 8];  // pad rows zero
      if ((int)(m / SSEQ) != bs) {
#pragma unroll
        for (int j = 0; j < 8; ++j) av[j] = 0;
      }
#pragma unroll
      for (int nf = 0; nf < 4; ++nf)
        acc[f8][nf] = __builtin_amdgcn_mfma_f32_16x16x32_bf16(av, gb[nf], acc[f8][nf], 0, 0, 0);
    }
  }

  // ---- epilogue: + bias, store fp32 ----
  float bv[4];
#pragma unroll
  for (int nf = 0; nf < 4; ++nf) bv[nf] = bias[n0 + wni * 64 + nf * 16 + l15];
#pragma unroll
  for (int f8 = 0; f8 < 8; ++f8) {
#pragma unroll
    for (int nf = 0; nf < 4; ++nf) {
      int n = n0 + wni * 64 + nf * 16 + l15;
#pragma unroll
      for (int r = 0; r < 4; ++r) {
        long long m = m0 + wmi * 128 + f8 * 16 + lhi * 4 + r;
        if (m < M_REAL) out[m * DDIM + n] = acc[f8][nf][r] + bv[nf];
      }
    }
  }
}

extern "C" void kernel_launch(void* const* d_in, const int* in_sizes, int n_in,
                              void* d_out, int out_size, void* d_ws, size_t ws_size,
                              hipStream_t stream) {
  const float* x      = (const float*)d_in[0];
  const int*   idx    = (const int*)d_in[1];
  const float* gates  = (const float*)d_in[2];
  const float* W      = (const float*)d_in[3];
  const float* A_all  = (const float*)d_in[4];
  const float* B_all  = (const float*)d_in[5];
  const float* bias   = (const float*)d_in[6];
  float* out = (float*)d_out;

  char* ws = (char*)d_ws;
  unsigned short* xbf  = (unsigned short*)(ws + XBF_OFF);
  unsigned short* wbf  = (unsigned short*)(ws + WBF_OFF);
  unsigned short* abf  = (unsigned short*)(ws + ABF_OFF);
  unsigned short* xabf = (unsigned short*)(ws + XABF_OFF);
  unsigned short* gbbf = (unsigned short*)(ws + GBBF_OFF);

  cast_x_kernel<<<dim3(2048), dim3(256), 0, stream>>>(x, xbf);
  prep_kernel<<<dim3(840), dim3(256), 0, stream>>>(W, A_all, B_all, idx, gates,
                                                   wbf, abf, gbbf, xabf);
  xa_kernel<<<dim3(640), dim3(256), 0, stream>>>(xbf, abf, idx, xabf);
  gemm_kernel<<<dim3(580), dim3(512), 0, stream>>>(xbf, wbf, xabf, gbbf, bias, out);
}

// Round 8
// 199.613 us; speedup vs baseline: 1.7552x; 1.1256x over previous
//
#include <hip/hip_runtime.h>
#include <hip/hip_bf16.h>
#include <stdint.h>

// Problem constants
#define M_REAL 36928LL      // 64*577
#define M_PAD  36992LL      // 289*128
#define DDIM   1024
#define SSEQ   577
#define NBATCH 64

typedef __attribute__((ext_vector_type(8))) short bf16x8;
typedef __attribute__((ext_vector_type(4))) float f32x4;

// ws layout (bytes)
#define XBF_OFF   0ULL                  // 36992*1024*2 = 75,759,616
#define WBF_OFF   75759616ULL           // 1024*1024*2  =  2,097,152
#define ABF_OFF   77856768ULL           // 8*16*1024*2  =    262,144
#define XABF_OFF  78118912ULL           // 36992*32*2   =  2,367,488
#define GBBF_OFF  80486400ULL           // 64*1024*32*2 =  4,194,304
#define WS_NEED   84680704ULL

__device__ __forceinline__ unsigned short f2bf(float f) {
  union { float f; unsigned int u; } v; v.f = f;
  unsigned int u = v.u;
  unsigned int r = (u + 0x7fffu + ((u >> 16) & 1u)) >> 16;  // RNE
  return (unsigned short)r;
}

__device__ __forceinline__ bf16x8 cvt8(const float* __restrict__ p) {
  float4 a = *(const float4*)p;
  float4 b = *(const float4*)(p + 4);
  bf16x8 o;
  o[0] = (short)f2bf(a.x); o[1] = (short)f2bf(a.y);
  o[2] = (short)f2bf(a.z); o[3] = (short)f2bf(a.w);
  o[4] = (short)f2bf(b.x); o[5] = (short)f2bf(b.y);
  o[6] = (short)f2bf(b.z); o[7] = (short)f2bf(b.w);
  return o;
}

#define GLOAD_LDS16(gsrc, ldst)                                                  \
  __builtin_amdgcn_global_load_lds((const __attribute__((address_space(1))) void*)(gsrc), \
                                   (__attribute__((address_space(3))) void*)(ldst), 16, 0, 0)

// ---------------- kernel 1: prep (cast W, cast A, build gB, zero pads) ------
__global__ void prep_kernel(const float* __restrict__ W,
                            const float* __restrict__ A_all,
                            const float* __restrict__ B_all,
                            const int* __restrict__ idx,
                            const float* __restrict__ gates,
                            unsigned short* __restrict__ wbf,
                            unsigned short* __restrict__ abf,
                            unsigned short* __restrict__ gbbf,
                            unsigned short* __restrict__ xbf,
                            unsigned short* __restrict__ xabf) {
  const int W_UNITS = 131072;                 // 8 elems each (1M total)
  const int A_UNITS = 16384;                  // 8 elems each (131072 total)
  const int G_UNITS = 65536;                  // one (b,n) row of 32 each
  const int XP_UNITS = 8192;                  // xbf pad rows (64 rows * 1024 / 8)
  const int P_UNITS = 2048;                   // xa pad elems (64 rows * 32)
  const int TOTAL = W_UNITS + A_UNITS + G_UNITS + XP_UNITS + P_UNITS; // 223232
  int u = blockIdx.x * blockDim.x + threadIdx.x;
  int stride = gridDim.x * blockDim.x;
  for (; u < TOTAL; u += stride) {
    if (u < W_UNITS) {
      int i = u * 8;
      *(bf16x8*)(wbf + i) = cvt8(W + i);
    } else if (u < W_UNITS + A_UNITS) {
      int i = (u - W_UNITS) * 8;
      *(bf16x8*)(abf + i) = cvt8(A_all + i);
    } else if (u < W_UNITS + A_UNITS + G_UNITS) {
      int v = u - W_UNITS - A_UNITS;
      int b = v >> 10;
      int n = v & 1023;
      unsigned short tmp[32];
#pragma unroll
      for (int k = 0; k < 2; ++k) {
        int e = idx[b * 2 + k];
        float g = gates[b * 2 + k];
        const float* Br = B_all + ((size_t)e * 1024 + n) * 16;
#pragma unroll
        for (int r = 0; r < 16; ++r) tmp[k * 16 + r] = f2bf(g * Br[r]);
      }
      unsigned short* dst = gbbf + (size_t)v * 32;
#pragma unroll
      for (int j = 0; j < 32; ++j) dst[j] = tmp[j];
    } else if (u < W_UNITS + A_UNITS + G_UNITS + XP_UNITS) {
      int v = u - W_UNITS - A_UNITS - G_UNITS;
      bf16x8 z;
#pragma unroll
      for (int j = 0; j < 8; ++j) z[j] = 0;
      *(bf16x8*)(xbf + (size_t)M_REAL * DDIM + (size_t)v * 8) = z;
    } else {
      int v = u - W_UNITS - A_UNITS - G_UNITS - XP_UNITS;
      xabf[(size_t)M_REAL * 32 + v] = 0;
    }
  }
}

// ---------------- kernel 2: fused cast x->bf16 + xa = x @ A_sel^T -----------
// Each block: one (b, s-chunk of 64 rows); 4 waves x 16 rows.
// Per k-step: lane loads 8 f32 of its row, cvt->bf16, writes xbf, feeds MFMA.
__global__ __launch_bounds__(256) void cast_xa_kernel(
    const float* __restrict__ x,
    const unsigned short* __restrict__ abf,
    const int* __restrict__ idx,
    unsigned short* __restrict__ xbf,
    unsigned short* __restrict__ xabf) {
  int bid = blockIdx.x;
  int b = bid / 10;
  int s0 = (bid % 10) * 64;
  int wave = threadIdx.x >> 6;
  int lane = threadIdx.x & 63;
  int l15 = lane & 15, lhi = lane >> 4;

  int srow = s0 + wave * 16 + l15;
  bool valid = srow < SSEQ;
  long long mrow = (long long)b * SSEQ + (valid ? srow : 0);
  const float* xrow = x + (size_t)mrow * DDIM;
  unsigned short* xbrow = xbf + (size_t)mrow * DDIM;
  int e0 = idx[b * 2 + 0], e1 = idx[b * 2 + 1];
  const unsigned short* ar0 = abf + ((size_t)e0 * 16 + l15) * DDIM;
  const unsigned short* ar1 = abf + ((size_t)e1 * 16 + l15) * DDIM;

  f32x4 acc0 = {0.f, 0.f, 0.f, 0.f}, acc1 = {0.f, 0.f, 0.f, 0.f};
  for (int k = 0; k < DDIM; k += 32) {
    int ko = k + lhi * 8;
    bf16x8 a;
    if (valid) {
      a = cvt8(xrow + ko);
      *(bf16x8*)(xbrow + ko) = a;
    } else {
#pragma unroll
      for (int j = 0; j < 8; ++j) a[j] = 0;
    }
    bf16x8 b0 = *(const bf16x8*)(ar0 + ko);
    bf16x8 b1 = *(const bf16x8*)(ar1 + ko);
    acc0 = __builtin_amdgcn_mfma_f32_16x16x32_bf16(a, b0, acc0, 0, 0, 0);
    acc1 = __builtin_amdgcn_mfma_f32_16x16x32_bf16(a, b1, acc1, 0, 0, 0);
  }
  // C layout: col = lane&15 (=r), row = (lane>>4)*4+reg
  int sout = s0 + wave * 16 + lhi * 4;
#pragma unroll
  for (int reg = 0; reg < 4; ++reg) {
    int s = sout + reg;
    if (s < SSEQ) {
      size_t mo = ((size_t)b * SSEQ + s) * 32;
      xabf[mo + l15]      = f2bf(acc0[reg]);
      xabf[mo + 16 + l15] = f2bf(acc1[reg]);
    }
  }
}

// ---------------- kernel 3: 128x128 m97-structure GEMM + swizzles -----------
// C[m,n] = sum_d x[m,d]*W[n,d] + bias[n] + sum_kr xa[m,kr]*gB[b(m),n,kr]
// r6 structure (best measured: 144us, 0 bank conflicts) + NT out stores.
#define BM 128
#define BN 128
#define BKT 64
__global__ __launch_bounds__(256, 4) void gemm_kernel(
    const unsigned short* __restrict__ xbf,
    const unsigned short* __restrict__ wbf,
    const unsigned short* __restrict__ xabf,
    const unsigned short* __restrict__ gbbf,
    const float* __restrict__ bias,
    float* __restrict__ out) {
  __shared__ unsigned short As[BM * BKT];   // 16 KiB
  __shared__ unsigned short Bs[BN * BKT];   // 16 KiB

  // XCD-chunked bijective swizzle: 2312 blocks = 8 XCDs x 289
  int g = blockIdx.x;
  int xcd = g & 7, gi = g >> 3;
  int wg = xcd * 289 + gi;
  const int bm = wg >> 3;              // 0..288
  const int bn = wg & 7;               // 0..7
  const long long m0 = (long long)bm * BM;
  const int n0 = bn * BN;

  const int tid = threadIdx.x;
  const int wave = tid >> 6, lane = tid & 63;
  const int l15 = lane & 15, lhi = lane >> 4;
  const int wm = (wave >> 1) * 64, wn = (wave & 1) * 64;

  f32x4 acc[4][4];
#pragma unroll
  for (int i = 0; i < 4; ++i)
#pragma unroll
    for (int j = 0; j < 4; ++j) acc[i][j] = (f32x4){0.f, 0.f, 0.f, 0.f};

  // staging: wave stages 32 rows; row = wave*32 + i*8 + (lane>>3), chunk=lane&7
  // swizzle: LDS[row][q] = global[row][q ^ (row&7)]; row&7 = lane>>3
  const int rowbase = wave * 32;
  const int rl = lane >> 3;
  const int csrc = (((lane & 7) ^ rl) << 3);   // elems

  // frag reads: desired chunk q = ks*4+lhi -> LDS chunk q ^ (l15&7)
  const int sl0 = ((lhi ^ (l15 & 7)) << 3);
  const int sl1 = sl0 ^ 32;

  for (int k0 = 0; k0 < DDIM; k0 += BKT) {
#pragma unroll
    for (int i = 0; i < 4; ++i) {
      int r = rowbase + i * 8;
      GLOAD_LDS16(xbf + (size_t)(m0 + r + rl) * DDIM + k0 + csrc, &As[r * BKT]);
      GLOAD_LDS16(wbf + (size_t)(n0 + r + rl) * DDIM + k0 + csrc, &Bs[r * BKT]);
    }
    __syncthreads();
    {
      bf16x8 af[4][2], bfv[4][2];
#pragma unroll
      for (int f = 0; f < 4; ++f) {
        af[f][0]  = *(const bf16x8*)&As[(wm + f * 16 + l15) * BKT + sl0];
        af[f][1]  = *(const bf16x8*)&As[(wm + f * 16 + l15) * BKT + sl1];
        bfv[f][0] = *(const bf16x8*)&Bs[(wn + f * 16 + l15) * BKT + sl0];
        bfv[f][1] = *(const bf16x8*)&Bs[(wn + f * 16 + l15) * BKT + sl1];
      }
#pragma unroll
      for (int i = 0; i < 4; ++i)
#pragma unroll
        for (int j = 0; j < 4; ++j)
#pragma unroll
          for (int ks = 0; ks < 2; ++ks)
            acc[i][j] = __builtin_amdgcn_mfma_f32_16x16x32_bf16(
                af[i][ks], bfv[j][ks], acc[i][j], 0, 0, 0);
    }
    __syncthreads();
  }

  // LoRA rank-32 extra K-steps, masked per batch (128-row tile spans <= 2)
  long long mlast = m0 + BM - 1; if (mlast > M_REAL - 1) mlast = M_REAL - 1;
  int b_lo = (int)(m0 / SSEQ);
  int b_hi = (int)(mlast / SSEQ);
  for (int bs = b_lo; bs <= b_hi; ++bs) {
    bf16x8 af[4], bfv[4];
#pragma unroll
    for (int f = 0; f < 4; ++f) {
      long long m = m0 + wm + f * 16 + l15;
      bf16x8 v = *(const bf16x8*)&xabf[(size_t)m * 32 + lhi * 8];  // pad rows zero
      if ((int)(m / SSEQ) != bs) {
#pragma unroll
        for (int j = 0; j < 8; ++j) v[j] = 0;
      }
      af[f] = v;
      int n = n0 + wn + f * 16 + l15;
      bfv[f] = *(const bf16x8*)&gbbf[((size_t)bs * 1024 + n) * 32 + lhi * 8];
    }
#pragma unroll
    for (int i = 0; i < 4; ++i)
#pragma unroll
      for (int j = 0; j < 4; ++j)
        acc[i][j] = __builtin_amdgcn_mfma_f32_16x16x32_bf16(af[i], bfv[j], acc[i][j], 0, 0, 0);
  }

  // epilogue: + bias, nontemporal fp32 stores
#pragma unroll
  for (int i = 0; i < 4; ++i) {
#pragma unroll
    for (int j = 0; j < 4; ++j) {
      int n = n0 + wn + j * 16 + l15;
      float bv = bias[n];
#pragma unroll
      for (int reg = 0; reg < 4; ++reg) {
        long long m = m0 + wm + i * 16 + lhi * 4 + reg;
        if (m < M_REAL)
          __builtin_nontemporal_store(acc[i][j][reg] + bv, &out[m * DDIM + n]);
      }
    }
  }
}

extern "C" void kernel_launch(void* const* d_in, const int* in_sizes, int n_in,
                              void* d_out, int out_size, void* d_ws, size_t ws_size,
                              hipStream_t stream) {
  const float* x      = (const float*)d_in[0];
  const int*   idx    = (const int*)d_in[1];
  const float* gates  = (const float*)d_in[2];
  const float* W      = (const float*)d_in[3];
  const float* A_all  = (const float*)d_in[4];
  const float* B_all  = (const float*)d_in[5];
  const float* bias   = (const float*)d_in[6];
  float* out = (float*)d_out;

  char* ws = (char*)d_ws;
  unsigned short* xbf  = (unsigned short*)(ws + XBF_OFF);
  unsigned short* wbf  = (unsigned short*)(ws + WBF_OFF);
  unsigned short* abf  = (unsigned short*)(ws + ABF_OFF);
  unsigned short* xabf = (unsigned short*)(ws + XABF_OFF);
  unsigned short* gbbf = (unsigned short*)(ws + GBBF_OFF);

  prep_kernel<<<dim3(872), dim3(256), 0, stream>>>(W, A_all, B_all, idx, gates,
                                                   wbf, abf, gbbf, xbf, xabf);
  cast_xa_kernel<<<dim3(640), dim3(256), 0, stream>>>(x, abf, idx, xbf, xabf);
  gemm_kernel<<<dim3(2312), dim3(256), 0, stream>>>(xbf, wbf, xabf, gbbf, bias, out);
}